// Round 8
// baseline (1587.045 us; speedup 1.0000x reference)
//
#include <hip/hip_runtime.h>
#include <hip/hip_bf16.h>
#include <math.h>

typedef __hip_bfloat16 bf16;

#define HB 8
#define HH 56
#define WWD 56
#define DD 256
#define NHEAD 8
#define KDIM 32
#define FFND 1024
#define NPIX (HB*HH*WWD)             /* 25088 */
#define SCALE_K 0.17677669529663687f /* 32^-0.5 */

__device__ inline float toF(float x){ return x; }
__device__ inline float toF(bf16 x){ return __bfloat162float(x); }

template<typename T> __device__ T fromF(float v);
template<> __device__ float fromF<float>(float v){ return v; }
template<> __device__ bf16  fromF<bf16>(float v){ return __float2bfloat16(v); }

// ---- depthwise conv (SAME, zero pad), optional +input. wst = weight channel stride ----
template<int KS, typename IT, typename OT, bool ADD>
__global__ __launch_bounds__(256) void dwconv_kernel(
    const IT* __restrict__ in, const float* __restrict__ wt, int wst,
    const float* __restrict__ bias, OT* __restrict__ out, int C)
{
    const int c = threadIdx.x;            // C == 256 always here
    const int p = blockIdx.x;
    const int w = p % WWD;
    const int h = (p / WWD) % HH;
    const int b = p / (WWD * HH);
    constexpr int P = KS / 2;
    float acc = bias[c];
    #pragma unroll
    for (int ky = 0; ky < KS; ky++) {
        int hh = h + ky - P;
        if (hh < 0 || hh >= HH) continue;
        #pragma unroll
        for (int kx = 0; kx < KS; kx++) {
            int ww = w + kx - P;
            if (ww < 0 || ww >= WWD) continue;
            acc += toF(in[((size_t)((b*HH + hh)*WWD + ww))*C + c]) * wt[(ky*KS + kx)*wst + c];
        }
    }
    if (ADD) acc += toF(in[(size_t)p*C + c]);
    out[(size_t)p*C + c] = fromF<OT>(acc);
}

// ---- LayerNorm over D=256, one block per token, bf16 out ----
__global__ __launch_bounds__(256) void ln_kernel(
    const float* __restrict__ x, const float* __restrict__ g,
    const float* __restrict__ b, bf16* __restrict__ out)
{
    const int t = blockIdx.x;
    const int c = threadIdx.x;
    float v = x[(size_t)t*DD + c];
    __shared__ float s1[256], s2[256];
    s1[c] = v; s2[c] = v*v;
    __syncthreads();
    for (int off = 128; off > 0; off >>= 1) {
        if (c < off) { s1[c] += s1[c+off]; s2[c] += s2[c+off]; }
        __syncthreads();
    }
    float mu  = s1[0] * (1.0f/DD);
    float var = s2[0] * (1.0f/DD) - mu*mu;
    float inv = rsqrtf(var + 1e-6f);
    out[(size_t)t*DD + c] = __float2bfloat16((v - mu) * inv * g[c] + b[c]);
}

// ---- GEMM: y = (dot(A_row, W_row) + bias[n]*bs) * scale;  A bf16, W fp32 (row stride ldw)
// EPI 0: outB = bf16(y)
// EPI 1: outB = bf16(gelu(y))
// EPI 2: accF[o] = residF[o] + y
// EPI 4: accF[o] += y
// EPI 5: outF[o] = accF[o] + y        (fp32 final output)
template<int EPI>
__global__ __launch_bounds__(256) void gemm_kernel(
    const bf16* __restrict__ A, const float* __restrict__ Wt, int ldw,
    const float* __restrict__ bias, float bs,
    const float* __restrict__ residF, float* accF, bf16* outB, float* outF,
    int M, int N, int K, float scale)
{
    __shared__ float As[16][65];
    __shared__ float Bs[16][65];
    const int tx = threadIdx.x, ty = threadIdx.y;
    const int tid = ty * 16 + tx;
    const int row0 = blockIdx.y * 64;
    const int col0 = blockIdx.x * 64;
    float c[4][4] = {};
    for (int k0 = 0; k0 < K; k0 += 16) {
        #pragma unroll
        for (int e = 0; e < 4; e++) {
            int li = tid*4 + e;
            int m = li >> 4, kk = li & 15;
            As[kk][m] = toF(A[(size_t)(row0 + m) * K + k0 + kk]);
        }
        #pragma unroll
        for (int e = 0; e < 4; e++) {
            int li = tid*4 + e;
            int n = li >> 4, kk = li & 15;
            Bs[kk][n] = Wt[(size_t)(col0 + n) * ldw + k0 + kk];
        }
        __syncthreads();
        #pragma unroll
        for (int kk = 0; kk < 16; kk++) {
            float a[4], bv[4];
            #pragma unroll
            for (int i = 0; i < 4; i++) a[i] = As[kk][ty*4 + i];
            #pragma unroll
            for (int j = 0; j < 4; j++) bv[j] = Bs[kk][tx*4 + j];
            #pragma unroll
            for (int i = 0; i < 4; i++)
                #pragma unroll
                for (int j = 0; j < 4; j++)
                    c[i][j] += a[i] * bv[j];
        }
        __syncthreads();
    }
    #pragma unroll
    for (int i = 0; i < 4; i++) {
        int m = row0 + ty*4 + i;
        #pragma unroll
        for (int j = 0; j < 4; j++) {
            int n = col0 + tx*4 + j;
            float y = (c[i][j] + bias[n]*bs) * scale;
            size_t o = (size_t)m * N + n;
            if (EPI == 0)      { outB[o] = __float2bfloat16(y); }
            else if (EPI == 1) { y = 0.5f*y*(1.0f + erff(y*0.70710678118654752f)); outB[o] = __float2bfloat16(y); }
            else if (EPI == 2) { accF[o] = residF[o] + y; }
            else if (EPI == 4) { accF[o] += y; }
            else if (EPI == 5) { outF[o] = accF[o] + y; }
        }
    }
}

// ---- RoPE (in place, q and k, bf16), phase = (h*W+w) * 10000^(-i/15) ----
__global__ __launch_bounds__(256) void rope_kernel(bf16* __restrict__ q, bf16* __restrict__ k)
{
    int id = blockIdx.x * 256 + threadIdx.x;  // N * NHEAD * 16 pairs
    int t  = id >> 7;
    int r  = id & 127;
    int nh = r >> 4;
    int i  = r & 15;
    int idx = t % (HH * WWD);
    float ang = powf(10000.0f, -(float)i * (1.0f/15.0f));
    float ph  = (float)idx * ang;
    float s = sinf(ph), cn = cosf(ph);
    size_t base = (size_t)t*DD + nh*KDIM + 2*i;
    float q0 = toF(q[base]), q1 = toF(q[base+1]);
    q[base]   = __float2bfloat16(q0*cn - q1*s);
    q[base+1] = __float2bfloat16(q1*cn + q0*s);
    float k0 = toF(k[base]), k1 = toF(k[base+1]);
    k[base]   = __float2bfloat16(k0*cn - k1*s);
    k[base+1] = __float2bfloat16(k1*cn + k0*s);
}

// ---- Row attention: per (b, nh, h), attend over W ----
__global__ __launch_bounds__(256) void row_attn_kernel(
    const bf16* __restrict__ q, const bf16* __restrict__ k,
    const bf16* __restrict__ v, bf16* __restrict__ vw)
{
    __shared__ float Qs[56][32], Ks[56][32], Vs[56][32];
    __shared__ float S[56][56];
    const int bid = blockIdx.x;
    const int h  = bid % HH;
    const int nh = (bid / HH) % NHEAD;
    const int b  = bid / (HH * NHEAD);
    const int tid = threadIdx.x;
    const size_t base = ((size_t)(b*HH + h) * WWD) * DD + nh*KDIM; // + w*DD + kd
    for (int t = tid; t < 56*32; t += 256) {
        int w_ = t >> 5, kd = t & 31;
        size_t g = base + (size_t)w_ * DD + kd;
        Qs[w_][kd] = toF(q[g]); Ks[w_][kd] = toF(k[g]); Vs[w_][kd] = toF(v[g]);
    }
    __syncthreads();
    for (int s = tid; s < 56*56; s += 256) {
        int i = s / 56, j = s - i*56;
        float acc = 0.f;
        #pragma unroll
        for (int d = 0; d < 32; d++) acc += Qs[i][d] * Ks[j][d];
        S[i][j] = acc;
    }
    __syncthreads();
    if (tid < 56) {
        float mx = -1e30f;
        for (int j = 0; j < 56; j++) mx = fmaxf(mx, S[tid][j]);
        float sum = 0.f;
        for (int j = 0; j < 56; j++) { float e = expf(S[tid][j] - mx); S[tid][j] = e; sum += e; }
        float inv = 1.0f / sum;
        for (int j = 0; j < 56; j++) S[tid][j] *= inv;
    }
    __syncthreads();
    for (int t = tid; t < 56*32; t += 256) {
        int i = t >> 5, d = t & 31;
        float acc = 0.f;
        for (int j = 0; j < 56; j++) acc += S[i][j] * Vs[j][d];
        vw[base + (size_t)i * DD + d] = __float2bfloat16(acc);
    }
}

// ---- Column attention per (b, nh, w) over H. Writes reference's
// ---- reshape-without-transpose SCRAMBLED layout, with lepe added there:
// ---- attn[b,n,h,w,d] -> out[b, 7n + h/8, (h%8)*7 + w/8, (w%8)*32 + d]
__global__ __launch_bounds__(256) void col_attn_kernel(
    const bf16* __restrict__ q, const bf16* __restrict__ k,
    const bf16* __restrict__ vw, const bf16* __restrict__ lepe,
    bf16* __restrict__ aout)
{
    __shared__ float Qs[56][32], Ks[56][32], Vs[56][32];
    __shared__ float S[56][56];
    const int bid = blockIdx.x;
    const int w  = bid % WWD;
    const int nh = (bid / WWD) % NHEAD;
    const int b  = bid / (WWD * NHEAD);
    const int tid = threadIdx.x;
    const size_t base = ((size_t)b*HH*WWD + w) * DD + nh*KDIM;   // + h*(W*D) + kd
    const size_t rstr = (size_t)WWD * DD;
    for (int t = tid; t < 56*32; t += 256) {
        int h_ = t >> 5, kd = t & 31;
        size_t g = base + (size_t)h_ * rstr + kd;
        Qs[h_][kd] = toF(q[g]); Ks[h_][kd] = toF(k[g]); Vs[h_][kd] = toF(vw[g]);
    }
    __syncthreads();
    for (int s = tid; s < 56*56; s += 256) {
        int i = s / 56, j = s - i*56;
        float acc = 0.f;
        #pragma unroll
        for (int d = 0; d < 32; d++) acc += Qs[i][d] * Ks[j][d];
        S[i][j] = acc;
    }
    __syncthreads();
    if (tid < 56) {
        float mx = -1e30f;
        for (int j = 0; j < 56; j++) mx = fmaxf(mx, S[tid][j]);
        float sum = 0.f;
        for (int j = 0; j < 56; j++) { float e = expf(S[tid][j] - mx); S[tid][j] = e; sum += e; }
        float inv = 1.0f / sum;
        for (int j = 0; j < 56; j++) S[tid][j] *= inv;
    }
    __syncthreads();
    for (int t = tid; t < 56*32; t += 256) {
        int i = t >> 5, d = t & 31;   // i = query h index
        float acc = 0.f;
        for (int j = 0; j < 56; j++) acc += S[i][j] * Vs[j][d];
        int hp = 7*nh + (i >> 3);
        int wp = (i & 7)*7 + (w >> 3);
        int cp = (w & 7)*32 + d;
        size_t o = ((size_t)(b*HH + hp)*WWD + wp)*DD + cp;
        aout[o] = __float2bfloat16(acc + toF(lepe[o]));
    }
}

extern "C" void kernel_launch(void* const* d_in, const int* in_sizes, int n_in,
                              void* d_out, int out_size, void* d_ws, size_t ws_size,
                              hipStream_t stream)
{
    const float* x_in   = (const float*)d_in[0];
    const float* cpe_w  = (const float*)d_in[1];
    const float* cpe_b  = (const float*)d_in[2];
    const float* ln1_g  = (const float*)d_in[3];
    const float* ln1_b  = (const float*)d_in[4];
    const float* wq     = (const float*)d_in[5];
    const float* bq     = (const float*)d_in[6];
    const float* wk     = (const float*)d_in[7];
    const float* bk     = (const float*)d_in[8];
    const float* wv     = (const float*)d_in[9];
    const float* bv     = (const float*)d_in[10];
    const float* lepe_w = (const float*)d_in[11];
    const float* lepe_b = (const float*)d_in[12];
    const float* wo     = (const float*)d_in[13];
    const float* bo     = (const float*)d_in[14];
    const float* ln2_g  = (const float*)d_in[15];
    const float* ln2_b  = (const float*)d_in[16];
    const float* fc1_w  = (const float*)d_in[17];
    const float* fc1_b  = (const float*)d_in[18];
    const float* dw_w   = (const float*)d_in[19];
    const float* dw_b   = (const float*)d_in[20];
    const float* fc2_w  = (const float*)d_in[21];
    const float* fc2_b  = (const float*)d_in[22];
    float* out = (float*)d_out;                 // OUTPUT IS FLOAT32 (proven R7 probe)

    const size_t ND = (size_t)NPIX * DD;
    // ws layout: 2 fp32 ND + 4 bf16 ND = ND*16 B = 102,760,448 B (<104.4 MB proven)
    float* X0  = (float*)d_ws;          // x after CPE (fp32 trunk residual 1)
    float* ACC = X0 + ND;               // fp32 x1 / fc2 accumulator
    bf16*  B1  = (bf16*)(ACC + ND);     // xn1, then lepe
    bf16*  B2  = B1 + ND;               // q roped, then xn2
    bf16*  B3  = B2 + ND;               // k roped, then h1q
    bf16*  B4  = B3 + ND;               // v, then h2q
    bf16*  VWb   = (bf16*)d_out;        // d_out scratch lo half: vw (bf16)
    bf16*  ATTNb = VWb + ND;            // d_out scratch hi half: attn scrambled (bf16)

    dim3 b256(256);
    dim3 gB(16, 16);
    dim3 gridD(DD/64, NPIX/64);   // (4, 392)

    // 1. CPE: X0 = x + dwconv3x3(x)            (fp32 trunk)
    dwconv_kernel<3, float, float, true><<<NPIX, b256, 0, stream>>>(x_in, cpe_w, DD, cpe_b, X0, DD);
    // 2. LN1 -> B1 (bf16)
    ln_kernel<<<NPIX, b256, 0, stream>>>(X0, ln1_g, ln1_b, B1);
    // 3-5. Q,K,V projections (SCALE folded into K)
    gemm_kernel<0><<<gridD, gB, 0, stream>>>(B1, wq, DD, bq, 1.0f, nullptr, nullptr, B2, nullptr, NPIX, DD, DD, 1.0f);
    gemm_kernel<0><<<gridD, gB, 0, stream>>>(B1, wk, DD, bk, 1.0f, nullptr, nullptr, B3, nullptr, NPIX, DD, DD, SCALE_K);
    gemm_kernel<0><<<gridD, gB, 0, stream>>>(B1, wv, DD, bv, 1.0f, nullptr, nullptr, B4, nullptr, NPIX, DD, DD, 1.0f);
    // 6. RoPE in place on q,k
    rope_kernel<<<(NPIX*128)/256, b256, 0, stream>>>(B2, B3);
    // 7. LEPE: B1 = dwconv5x5(v)   (xn1 dead)
    dwconv_kernel<5, bf16, bf16, false><<<NPIX, b256, 0, stream>>>(B4, lepe_w, DD, lepe_b, B1, DD);
    // 8. Row attention: (q,k,v) -> vw (d_out lo scratch)
    row_attn_kernel<<<HB*NHEAD*HH, b256, 0, stream>>>(B2, B3, B4, VWb);
    // 9. Column attention on vw; scrambled write + lepe -> ATTNb (d_out hi scratch)
    col_attn_kernel<<<HB*NHEAD*WWD, b256, 0, stream>>>(B2, B3, VWb, B1, ATTNb);
    // 10. Output projection + residual: ACC = X0 + ATTNb*wo^T + bo
    gemm_kernel<2><<<gridD, gB, 0, stream>>>(ATTNb, wo, DD, bo, 1.0f, X0, ACC, nullptr, nullptr, NPIX, DD, DD, 1.0f);
    // 11. LN2 -> B2 (q dead)
    ln_kernel<<<NPIX, b256, 0, stream>>>(ACC, ln2_g, ln2_b, B2);
    // 12-14 x4: FFN in four 256-channel quarters, fc2 accumulated into ACC
    for (int qtr = 0; qtr < 4; qtr++) {
        const int off = qtr * 256;
        // 12q. h1q = gelu(xn2 . fc1_w[off:off+256]^T + fc1_b[off:]) -> B3 (k dead)
        gemm_kernel<1><<<gridD, gB, 0, stream>>>(B2, fc1_w + (size_t)off*DD, DD, fc1_b + off, 1.0f,
                                                 nullptr, nullptr, B3, nullptr, NPIX, 256, DD, 1.0f);
        // 13q. h2q = dwconv3x3(h1q) + h1q -> B4 (v dead); weights strided by FFND
        dwconv_kernel<3, bf16, bf16, true><<<NPIX, b256, 0, stream>>>(B3, dw_w + off, FFND, dw_b + off, B4, 256);
        // 14q. fc2 partial: ACC += h2q . fc2_w[:, off:off+256]^T (+bias once; final qtr -> fp32 out)
        if (qtr < 3)
            gemm_kernel<4><<<gridD, gB, 0, stream>>>(B4, fc2_w + off, FFND, fc2_b, (qtr==0)?1.0f:0.0f,
                                                     nullptr, ACC, nullptr, nullptr, NPIX, DD, 256, 1.0f);
        else
            gemm_kernel<5><<<gridD, gB, 0, stream>>>(B4, fc2_w + off, FFND, fc2_b, 0.0f,
                                                     nullptr, ACC, nullptr, out, NPIX, DD, 256, 1.0f);
    }
}

// Round 9
// 836.420 us; speedup vs baseline: 1.8974x; 1.8974x over previous
//
#include <hip/hip_runtime.h>
#include <hip/hip_bf16.h>
#include <math.h>

typedef __hip_bfloat16 bf16;

#define HB 8
#define HH 56
#define WWD 56
#define DD 256
#define NHEAD 8
#define KDIM 32
#define FFND 1024
#define NPIX (HB*HH*WWD)             /* 25088 */
#define SCALE_K 0.17677669529663687f /* 32^-0.5 */

typedef __attribute__((ext_vector_type(8))) short short8;   // 8 bf16 (4 VGPRs)
typedef __attribute__((ext_vector_type(4))) float f32x4;

__device__ inline float toF(float x){ return x; }
__device__ inline float toF(bf16 x){ return __bfloat162float(x); }

template<typename T> __device__ T fromF(float v);
template<> __device__ float fromF<float>(float v){ return v; }
template<> __device__ bf16  fromF<bf16>(float v){ return __float2bfloat16(v); }

__device__ inline unsigned short f2bu(float f){
    union { bf16 b; unsigned short u; } cv; cv.b = __float2bfloat16(f); return cv.u;
}
__device__ inline unsigned pk2(float a, float b){
    return (unsigned)f2bu(a) | ((unsigned)f2bu(b) << 16);
}

// ---- depthwise conv (SAME, zero pad), optional +input. wst = weight channel stride ----
template<int KS, typename IT, typename OT, bool ADD>
__global__ __launch_bounds__(256) void dwconv_kernel(
    const IT* __restrict__ in, const float* __restrict__ wt, int wst,
    const float* __restrict__ bias, OT* __restrict__ out, int C)
{
    const int c = threadIdx.x;
    const int p = blockIdx.x;
    const int w = p % WWD;
    const int h = (p / WWD) % HH;
    const int b = p / (WWD * HH);
    constexpr int P = KS / 2;
    float acc = bias[c];
    #pragma unroll
    for (int ky = 0; ky < KS; ky++) {
        int hh = h + ky - P;
        if (hh < 0 || hh >= HH) continue;
        #pragma unroll
        for (int kx = 0; kx < KS; kx++) {
            int ww = w + kx - P;
            if (ww < 0 || ww >= WWD) continue;
            acc += toF(in[((size_t)((b*HH + hh)*WWD + ww))*C + c]) * wt[(ky*KS + kx)*wst + c];
        }
    }
    if (ADD) acc += toF(in[(size_t)p*C + c]);
    out[(size_t)p*C + c] = fromF<OT>(acc);
}

// ---- LayerNorm over D=256, one block per token, bf16 out ----
__global__ __launch_bounds__(256) void ln_kernel(
    const float* __restrict__ x, const float* __restrict__ g,
    const float* __restrict__ b, bf16* __restrict__ out)
{
    const int t = blockIdx.x;
    const int c = threadIdx.x;
    float v = x[(size_t)t*DD + c];
    __shared__ float s1[256], s2[256];
    s1[c] = v; s2[c] = v*v;
    __syncthreads();
    for (int off = 128; off > 0; off >>= 1) {
        if (c < off) { s1[c] += s1[c+off]; s2[c] += s2[c+off]; }
        __syncthreads();
    }
    float mu  = s1[0] * (1.0f/DD);
    float var = s2[0] * (1.0f/DD) - mu*mu;
    float inv = rsqrtf(var + 1e-6f);
    out[(size_t)t*DD + c] = __float2bfloat16((v - mu) * inv * g[c] + b[c]);
}

// ---- MFMA GEMM: y = (dot(A_row, W_row) + bias[n]*bs) * scale
//   A bf16 [M,K], W fp32 [N rows, ldw stride] (row-major, W[n][k])
//   64x64 tile, 4 waves, each wave 16 rows x 64 cols via 4 16x16x32 MFMA accs.
// EPI 0: outB = bf16(y);  1: outB = bf16(gelu(y));  2: accF = residF + y;
//     4: accF += y;       5: outF = accF + y (fp32 final)
template<int EPI>
__global__ __launch_bounds__(256) void mgemm_kernel(
    const bf16* __restrict__ A, const float* __restrict__ Wt, int ldw,
    const float* __restrict__ bias, float bs,
    const float* __restrict__ residF, float* accF, bf16* outB, float* outF,
    int M, int N, int K, float scale)
{
    __shared__ unsigned short As[64*40];   // row stride 40 bf16 (pad 32->40: conflict-free b128)
    __shared__ unsigned short Bs[64*40];
    const int tid  = threadIdx.x;
    const int wave = tid >> 6;
    const int lane = tid & 63;
    const int quad = lane >> 4;
    const int l15  = lane & 15;
    const int row0 = blockIdx.y * 64;
    const int col0 = blockIdx.x * 64;

    f32x4 acc[4];
    #pragma unroll
    for (int j = 0; j < 4; j++) acc[j] = (f32x4){0.f, 0.f, 0.f, 0.f};

    const int r  = tid >> 2;   // 0..63 (tile row / weight row)
    const int cc = tid & 3;    // 0..3  (k-chunk of 8)

    for (int k0 = 0; k0 < K; k0 += 32) {
        // stage A tile: 64 rows x 32 k, 8 bf16 (16B) per thread
        {
            const uint4* src = (const uint4*)(A + (size_t)(row0 + r) * K + k0 + cc*8);
            *(uint4*)(&As[r*40 + cc*8]) = *src;
        }
        // stage B tile: W[n][k] fp32 -> bf16
        {
            const float* s = Wt + (size_t)(col0 + r) * ldw + k0 + cc*8;
            float4 f0 = *(const float4*)(s);
            float4 f1 = *(const float4*)(s + 4);
            uint4 v;
            v.x = pk2(f0.x, f0.y); v.y = pk2(f0.z, f0.w);
            v.z = pk2(f1.x, f1.y); v.w = pk2(f1.z, f1.w);
            *(uint4*)(&Bs[r*40 + cc*8]) = v;
        }
        __syncthreads();
        short8 af = *(const short8*)(&As[(wave*16 + l15)*40 + quad*8]);
        #pragma unroll
        for (int j = 0; j < 4; j++) {
            short8 bf_ = *(const short8*)(&Bs[(j*16 + l15)*40 + quad*8]);
            acc[j] = __builtin_amdgcn_mfma_f32_16x16x32_bf16(af, bf_, acc[j], 0, 0, 0);
        }
        __syncthreads();
    }

    // epilogue: element (j, reg) -> m = row0+wave*16+quad*4+reg, n = col0+16j+l15
    #pragma unroll
    for (int j = 0; j < 4; j++) {
        const int n = col0 + 16*j + l15;
        const float bval = bias[n] * bs;
        #pragma unroll
        for (int reg = 0; reg < 4; reg++) {
            const int m = row0 + wave*16 + quad*4 + reg;
            float y = (acc[j][reg] + bval) * scale;
            size_t o = (size_t)m * N + n;
            if (EPI == 0)      { outB[o] = __float2bfloat16(y); }
            else if (EPI == 1) { y = 0.5f*y*(1.0f + erff(y*0.70710678118654752f)); outB[o] = __float2bfloat16(y); }
            else if (EPI == 2) { accF[o] = residF[o] + y; }
            else if (EPI == 4) { accF[o] += y; }
            else if (EPI == 5) { outF[o] = accF[o] + y; }
        }
    }
}

// ---- RoPE (in place, q and k, bf16), phase = (h*W+w) * 10000^(-i/15) ----
__global__ __launch_bounds__(256) void rope_kernel(bf16* __restrict__ q, bf16* __restrict__ k)
{
    int id = blockIdx.x * 256 + threadIdx.x;
    int t  = id >> 7;
    int r  = id & 127;
    int nh = r >> 4;
    int i  = r & 15;
    int idx = t % (HH * WWD);
    float ang = powf(10000.0f, -(float)i * (1.0f/15.0f));
    float ph  = (float)idx * ang;
    float s = sinf(ph), cn = cosf(ph);
    size_t base = (size_t)t*DD + nh*KDIM + 2*i;
    float q0 = toF(q[base]), q1 = toF(q[base+1]);
    q[base]   = __float2bfloat16(q0*cn - q1*s);
    q[base+1] = __float2bfloat16(q1*cn + q0*s);
    float k0 = toF(k[base]), k1 = toF(k[base+1]);
    k[base]   = __float2bfloat16(k0*cn - k1*s);
    k[base+1] = __float2bfloat16(k1*cn + k0*s);
}

// ---- Row attention: per (b, nh, h), attend over W. Padded LDS (33/57). ----
__global__ __launch_bounds__(256) void row_attn_kernel(
    const bf16* __restrict__ q, const bf16* __restrict__ k,
    const bf16* __restrict__ v, bf16* __restrict__ vw)
{
    __shared__ float Qs[56][33], Ks[56][33], Vs[56][33];
    __shared__ float S[56][57];
    const int bid = blockIdx.x;
    const int h  = bid % HH;
    const int nh = (bid / HH) % NHEAD;
    const int b  = bid / (HH * NHEAD);
    const int tid = threadIdx.x;
    const size_t base = ((size_t)(b*HH + h) * WWD) * DD + nh*KDIM;
    for (int t = tid; t < 56*32; t += 256) {
        int w_ = t >> 5, kd = t & 31;
        size_t g = base + (size_t)w_ * DD + kd;
        Qs[w_][kd] = toF(q[g]); Ks[w_][kd] = toF(k[g]); Vs[w_][kd] = toF(v[g]);
    }
    __syncthreads();
    for (int s = tid; s < 56*56; s += 256) {
        int i = s / 56, j = s - i*56;
        float acc = 0.f;
        #pragma unroll
        for (int d = 0; d < 32; d++) acc += Qs[i][d] * Ks[j][d];
        S[i][j] = acc;
    }
    __syncthreads();
    if (tid < 56) {
        float mx = -1e30f;
        for (int j = 0; j < 56; j++) mx = fmaxf(mx, S[tid][j]);
        float sum = 0.f;
        for (int j = 0; j < 56; j++) { float e = expf(S[tid][j] - mx); S[tid][j] = e; sum += e; }
        float inv = 1.0f / sum;
        for (int j = 0; j < 56; j++) S[tid][j] *= inv;
    }
    __syncthreads();
    for (int t = tid; t < 56*32; t += 256) {
        int i = t >> 5, d = t & 31;
        float acc = 0.f;
        for (int j = 0; j < 56; j++) acc += S[i][j] * Vs[j][d];
        vw[base + (size_t)i * DD + d] = __float2bfloat16(acc);
    }
}

// ---- Column attention per (b, nh, w) over H; scrambled write + lepe. Padded LDS. ----
__global__ __launch_bounds__(256) void col_attn_kernel(
    const bf16* __restrict__ q, const bf16* __restrict__ k,
    const bf16* __restrict__ vw, const bf16* __restrict__ lepe,
    bf16* __restrict__ aout)
{
    __shared__ float Qs[56][33], Ks[56][33], Vs[56][33];
    __shared__ float S[56][57];
    const int bid = blockIdx.x;
    const int w  = bid % WWD;
    const int nh = (bid / WWD) % NHEAD;
    const int b  = bid / (WWD * NHEAD);
    const int tid = threadIdx.x;
    const size_t base = ((size_t)b*HH*WWD + w) * DD + nh*KDIM;
    const size_t rstr = (size_t)WWD * DD;
    for (int t = tid; t < 56*32; t += 256) {
        int h_ = t >> 5, kd = t & 31;
        size_t g = base + (size_t)h_ * rstr + kd;
        Qs[h_][kd] = toF(q[g]); Ks[h_][kd] = toF(k[g]); Vs[h_][kd] = toF(vw[g]);
    }
    __syncthreads();
    for (int s = tid; s < 56*56; s += 256) {
        int i = s / 56, j = s - i*56;
        float acc = 0.f;
        #pragma unroll
        for (int d = 0; d < 32; d++) acc += Qs[i][d] * Ks[j][d];
        S[i][j] = acc;
    }
    __syncthreads();
    if (tid < 56) {
        float mx = -1e30f;
        for (int j = 0; j < 56; j++) mx = fmaxf(mx, S[tid][j]);
        float sum = 0.f;
        for (int j = 0; j < 56; j++) { float e = expf(S[tid][j] - mx); S[tid][j] = e; sum += e; }
        float inv = 1.0f / sum;
        for (int j = 0; j < 56; j++) S[tid][j] *= inv;
    }
    __syncthreads();
    for (int t = tid; t < 56*32; t += 256) {
        int i = t >> 5, d = t & 31;
        float acc = 0.f;
        for (int j = 0; j < 56; j++) acc += S[i][j] * Vs[j][d];
        int hp = 7*nh + (i >> 3);
        int wp = (i & 7)*7 + (w >> 3);
        int cp = (w & 7)*32 + d;
        size_t o = ((size_t)(b*HH + hp)*WWD + wp)*DD + cp;
        aout[o] = __float2bfloat16(acc + toF(lepe[o]));
    }
}

extern "C" void kernel_launch(void* const* d_in, const int* in_sizes, int n_in,
                              void* d_out, int out_size, void* d_ws, size_t ws_size,
                              hipStream_t stream)
{
    const float* x_in   = (const float*)d_in[0];
    const float* cpe_w  = (const float*)d_in[1];
    const float* cpe_b  = (const float*)d_in[2];
    const float* ln1_g  = (const float*)d_in[3];
    const float* ln1_b  = (const float*)d_in[4];
    const float* wq     = (const float*)d_in[5];
    const float* bq     = (const float*)d_in[6];
    const float* wk     = (const float*)d_in[7];
    const float* bk     = (const float*)d_in[8];
    const float* wv     = (const float*)d_in[9];
    const float* bv     = (const float*)d_in[10];
    const float* lepe_w = (const float*)d_in[11];
    const float* lepe_b = (const float*)d_in[12];
    const float* wo     = (const float*)d_in[13];
    const float* bo     = (const float*)d_in[14];
    const float* ln2_g  = (const float*)d_in[15];
    const float* ln2_b  = (const float*)d_in[16];
    const float* fc1_w  = (const float*)d_in[17];
    const float* fc1_b  = (const float*)d_in[18];
    const float* dw_w   = (const float*)d_in[19];
    const float* dw_b   = (const float*)d_in[20];
    const float* fc2_w  = (const float*)d_in[21];
    const float* fc2_b  = (const float*)d_in[22];
    float* out = (float*)d_out;                 // fp32 output (proven R7/R8)

    const size_t ND = (size_t)NPIX * DD;
    float* X0  = (float*)d_ws;          // fp32 trunk residual 1
    float* ACC = X0 + ND;               // fp32 x1 / fc2 accumulator
    bf16*  B1  = (bf16*)(ACC + ND);     // xn1, then lepe
    bf16*  B2  = B1 + ND;               // q roped, then xn2
    bf16*  B3  = B2 + ND;               // k roped, then h1q
    bf16*  B4  = B3 + ND;               // v, then h2q
    bf16*  VWb   = (bf16*)d_out;        // d_out lo half: vw scratch
    bf16*  ATTNb = VWb + ND;            // d_out hi half: attn scrambled scratch

    dim3 b256(256);
    dim3 gridD(DD/64, NPIX/64);   // (4, 392) — N=256 for every GEMM here

    // 1. CPE: X0 = x + dwconv3x3(x)
    dwconv_kernel<3, float, float, true><<<NPIX, b256, 0, stream>>>(x_in, cpe_w, DD, cpe_b, X0, DD);
    // 2. LN1 -> B1
    ln_kernel<<<NPIX, b256, 0, stream>>>(X0, ln1_g, ln1_b, B1);
    // 3-5. Q,K,V projections (SCALE folded into K)
    mgemm_kernel<0><<<gridD, b256, 0, stream>>>(B1, wq, DD, bq, 1.0f, nullptr, nullptr, B2, nullptr, NPIX, DD, DD, 1.0f);
    mgemm_kernel<0><<<gridD, b256, 0, stream>>>(B1, wk, DD, bk, 1.0f, nullptr, nullptr, B3, nullptr, NPIX, DD, DD, SCALE_K);
    mgemm_kernel<0><<<gridD, b256, 0, stream>>>(B1, wv, DD, bv, 1.0f, nullptr, nullptr, B4, nullptr, NPIX, DD, DD, 1.0f);
    // 6. RoPE in place on q,k
    rope_kernel<<<(NPIX*128)/256, b256, 0, stream>>>(B2, B3);
    // 7. LEPE: B1 = dwconv5x5(v)
    dwconv_kernel<5, bf16, bf16, false><<<NPIX, b256, 0, stream>>>(B4, lepe_w, DD, lepe_b, B1, DD);
    // 8. Row attention: (q,k,v) -> vw
    row_attn_kernel<<<HB*NHEAD*HH, b256, 0, stream>>>(B2, B3, B4, VWb);
    // 9. Column attention; scrambled write + lepe -> ATTNb
    col_attn_kernel<<<HB*NHEAD*WWD, b256, 0, stream>>>(B2, B3, VWb, B1, ATTNb);
    // 10. Output projection + residual: ACC = X0 + ATTNb*wo^T + bo
    mgemm_kernel<2><<<gridD, b256, 0, stream>>>(ATTNb, wo, DD, bo, 1.0f, X0, ACC, nullptr, nullptr, NPIX, DD, DD, 1.0f);
    // 11. LN2 -> B2
    ln_kernel<<<NPIX, b256, 0, stream>>>(ACC, ln2_g, ln2_b, B2);
    // 12-14 x4: FFN in four 256-channel quarters, fc2 accumulated into ACC
    for (int qtr = 0; qtr < 4; qtr++) {
        const int off = qtr * 256;
        mgemm_kernel<1><<<gridD, b256, 0, stream>>>(B2, fc1_w + (size_t)off*DD, DD, fc1_b + off, 1.0f,
                                                    nullptr, nullptr, B3, nullptr, NPIX, 256, DD, 1.0f);
        dwconv_kernel<3, bf16, bf16, true><<<NPIX, b256, 0, stream>>>(B3, dw_w + off, FFND, dw_b + off, B4, 256);
        if (qtr < 3)
            mgemm_kernel<4><<<gridD, b256, 0, stream>>>(B4, fc2_w + off, FFND, fc2_b, (qtr==0)?1.0f:0.0f,
                                                        nullptr, ACC, nullptr, nullptr, NPIX, DD, 256, 1.0f);
        else
            mgemm_kernel<5><<<gridD, b256, 0, stream>>>(B4, fc2_w + off, FFND, fc2_b, 0.0f,
                                                        nullptr, ACC, nullptr, out, NPIX, DD, 256, 1.0f);
    }
}

// Round 10
// 759.856 us; speedup vs baseline: 2.0886x; 1.1008x over previous
//
#include <hip/hip_runtime.h>
#include <hip/hip_bf16.h>
#include <math.h>

typedef __hip_bfloat16 bf16;

#define HB 8
#define HH 56
#define WWD 56
#define DD 256
#define NHEAD 8
#define KDIM 32
#define FFND 1024
#define NPIX (HB*HH*WWD)             /* 25088 */
#define SCALE_K 0.17677669529663687f /* 32^-0.5 */

typedef __attribute__((ext_vector_type(8))) short short8;   // 8 bf16 (4 VGPRs)
typedef __attribute__((ext_vector_type(4))) float f32x4;

__device__ inline float toF(float x){ return x; }
__device__ inline float toF(bf16 x){ return __bfloat162float(x); }

template<typename T> __device__ T fromF(float v);
template<> __device__ float fromF<float>(float v){ return v; }
template<> __device__ bf16  fromF<bf16>(float v){ return __float2bfloat16(v); }

__device__ inline unsigned short f2bu(float f){
    union { bf16 b; unsigned short u; } cv; cv.b = __float2bfloat16(f); return cv.u;
}
__device__ inline unsigned pk2(float a, float b){
    return (unsigned)f2bu(a) | ((unsigned)f2bu(b) << 16);
}

// ---- depthwise conv (SAME, zero pad), optional +input. wst = weight channel stride ----
template<int KS, typename IT, typename OT, bool ADD>
__global__ __launch_bounds__(256) void dwconv_kernel(
    const IT* __restrict__ in, const float* __restrict__ wt, int wst,
    const float* __restrict__ bias, OT* __restrict__ out, int C)
{
    const int c = threadIdx.x;
    const int p = blockIdx.x;
    const int w = p % WWD;
    const int h = (p / WWD) % HH;
    const int b = p / (WWD * HH);
    constexpr int P = KS / 2;
    float acc = bias[c];
    #pragma unroll
    for (int ky = 0; ky < KS; ky++) {
        int hh = h + ky - P;
        if (hh < 0 || hh >= HH) continue;
        #pragma unroll
        for (int kx = 0; kx < KS; kx++) {
            int ww = w + kx - P;
            if (ww < 0 || ww >= WWD) continue;
            acc += toF(in[((size_t)((b*HH + hh)*WWD + ww))*C + c]) * wt[(ky*KS + kx)*wst + c];
        }
    }
    if (ADD) acc += toF(in[(size_t)p*C + c]);
    out[(size_t)p*C + c] = fromF<OT>(acc);
}

// ---- LayerNorm over D=256, one block per token, bf16 out ----
__global__ __launch_bounds__(256) void ln_kernel(
    const float* __restrict__ x, const float* __restrict__ g,
    const float* __restrict__ b, bf16* __restrict__ out)
{
    const int t = blockIdx.x;
    const int c = threadIdx.x;
    float v = x[(size_t)t*DD + c];
    __shared__ float s1[256], s2[256];
    s1[c] = v; s2[c] = v*v;
    __syncthreads();
    for (int off = 128; off > 0; off >>= 1) {
        if (c < off) { s1[c] += s1[c+off]; s2[c] += s2[c+off]; }
        __syncthreads();
    }
    float mu  = s1[0] * (1.0f/DD);
    float var = s2[0] * (1.0f/DD) - mu*mu;
    float inv = rsqrtf(var + 1e-6f);
    out[(size_t)t*DD + c] = __float2bfloat16((v - mu) * inv * g[c] + b[c]);
}

// ---- MFMA GEMM (same as R9): 64x64 tile, 4 waves, 16x16x32 bf16 ----
template<int EPI>
__global__ __launch_bounds__(256) void mgemm_kernel(
    const bf16* __restrict__ A, const float* __restrict__ Wt, int ldw,
    const float* __restrict__ bias, float bs,
    const float* __restrict__ residF, float* accF, bf16* outB, float* outF,
    int M, int N, int K, float scale)
{
    __shared__ unsigned short As[64*40];
    __shared__ unsigned short Bs[64*40];
    const int tid  = threadIdx.x;
    const int wave = tid >> 6;
    const int lane = tid & 63;
    const int quad = lane >> 4;
    const int l15  = lane & 15;
    const int row0 = blockIdx.y * 64;
    const int col0 = blockIdx.x * 64;

    f32x4 acc[4];
    #pragma unroll
    for (int j = 0; j < 4; j++) acc[j] = (f32x4){0.f, 0.f, 0.f, 0.f};

    const int r  = tid >> 2;
    const int cc = tid & 3;

    for (int k0 = 0; k0 < K; k0 += 32) {
        {
            const uint4* src = (const uint4*)(A + (size_t)(row0 + r) * K + k0 + cc*8);
            *(uint4*)(&As[r*40 + cc*8]) = *src;
        }
        {
            const float* s = Wt + (size_t)(col0 + r) * ldw + k0 + cc*8;
            float4 f0 = *(const float4*)(s);
            float4 f1 = *(const float4*)(s + 4);
            uint4 v;
            v.x = pk2(f0.x, f0.y); v.y = pk2(f0.z, f0.w);
            v.z = pk2(f1.x, f1.y); v.w = pk2(f1.z, f1.w);
            *(uint4*)(&Bs[r*40 + cc*8]) = v;
        }
        __syncthreads();
        short8 af = *(const short8*)(&As[(wave*16 + l15)*40 + quad*8]);
        #pragma unroll
        for (int j = 0; j < 4; j++) {
            short8 bf_ = *(const short8*)(&Bs[(j*16 + l15)*40 + quad*8]);
            acc[j] = __builtin_amdgcn_mfma_f32_16x16x32_bf16(af, bf_, acc[j], 0, 0, 0);
        }
        __syncthreads();
    }

    #pragma unroll
    for (int j = 0; j < 4; j++) {
        const int n = col0 + 16*j + l15;
        const float bval = bias[n] * bs;
        #pragma unroll
        for (int reg = 0; reg < 4; reg++) {
            const int m = row0 + wave*16 + quad*4 + reg;
            float y = (acc[j][reg] + bval) * scale;
            size_t o = (size_t)m * N + n;
            if (EPI == 0)      { outB[o] = __float2bfloat16(y); }
            else if (EPI == 1) { y = 0.5f*y*(1.0f + erff(y*0.70710678118654752f)); outB[o] = __float2bfloat16(y); }
            else if (EPI == 2) { accF[o] = residF[o] + y; }
            else if (EPI == 4) { accF[o] += y; }
            else if (EPI == 5) { outF[o] = accF[o] + y; }
        }
    }
}

// ---- RoPE (in place, q and k, bf16) ----
__global__ __launch_bounds__(256) void rope_kernel(bf16* __restrict__ q, bf16* __restrict__ k)
{
    int id = blockIdx.x * 256 + threadIdx.x;
    int t  = id >> 7;
    int r  = id & 127;
    int nh = r >> 4;
    int i  = r & 15;
    int idx = t % (HH * WWD);
    float ang = powf(10000.0f, -(float)i * (1.0f/15.0f));
    float ph  = (float)idx * ang;
    float s = sinf(ph), cn = cosf(ph);
    size_t base = (size_t)t*DD + nh*KDIM + 2*i;
    float q0 = toF(q[base]), q1 = toF(q[base+1]);
    q[base]   = __float2bfloat16(q0*cn - q1*s);
    q[base+1] = __float2bfloat16(q1*cn + q0*s);
    float k0 = toF(k[base]), k1 = toF(k[base+1]);
    k[base]   = __float2bfloat16(k0*cn - k1*s);
    k[base+1] = __float2bfloat16(k1*cn + k0*s);
}

// ---- MFMA decomposed attention. One block per (b, nh, line).
// ROW mode (COLM=0): line = h, attend over w (stride DD);  out = vw, plain write.
// COL mode (COLM=1): line = w, attend over h (stride W*D); out = scrambled + lepe.
// S = Q·K^T via 16x16x32 MFMA (pad 56->64), masked softmax, P->bf16 LDS, P·V via MFMA.
template<bool COLM>
__global__ __launch_bounds__(256) void attn_mfma_kernel(
    const bf16* __restrict__ q, const bf16* __restrict__ k,
    const bf16* __restrict__ v, const bf16* __restrict__ lepe,
    bf16* __restrict__ outp)
{
    __shared__ unsigned short Qb[64*40];   // Q[j][d]   row-major, pad 40
    __shared__ unsigned short Kb[64*40];   // K[j][d]   row-major
    __shared__ unsigned short Vt[32*80];   // V^T[d][j] (j padded to 64, stride 80)
    __shared__ float S[64*57];             // scores / probabilities
    __shared__ unsigned short Pb[64*72];   // P bf16, k-padded to 64

    const int bid  = blockIdx.x;
    const int line = bid % 56;
    const int nh   = (bid / 56) % NHEAD;
    const int b    = bid / (56 * NHEAD);
    const int tid  = threadIdx.x;
    const int wid  = tid >> 6;
    const int lane = tid & 63;
    const int quad = lane >> 4;
    const int l15  = lane & 15;

    const size_t rstr = COLM ? (size_t)WWD * DD : (size_t)DD;
    const size_t base = COLM ? (((size_t)b*HH*WWD + line) * DD + nh*KDIM)
                             : (((size_t)(b*HH + line) * WWD) * DD + nh*KDIM);

    // ---- stage Q, K (row-major) and V transposed; zero pads ----
    {
        const int r  = tid >> 2;      // 0..63
        const int cc = tid & 3;       // 16B chunk of the 32-elem row
        uint4 zero = {0,0,0,0};
        if (r < 56) {
            size_t g = base + (size_t)r * rstr + cc*8;
            *(uint4*)(&Qb[r*40 + cc*8]) = *(const uint4*)(q + g);
            *(uint4*)(&Kb[r*40 + cc*8]) = *(const uint4*)(k + g);
        } else {
            *(uint4*)(&Qb[r*40 + cc*8]) = zero;
            *(uint4*)(&Kb[r*40 + cc*8]) = zero;
        }
        for (int t = tid; t < 56*32; t += 256) {
            int j = t >> 5, d = t & 31;
            union { bf16 b_; unsigned short u; } cv;
            cv.b_ = v[base + (size_t)j * rstr + d];
            Vt[d*80 + j] = cv.u;
        }
        { // zero pad columns j = 56..63 (NaN-safety for the PV k-pad)
            int j = 56 + (tid >> 5), d = tid & 31;
            Vt[d*80 + j] = 0;
        }
    }
    __syncthreads();

    // ---- QK^T: wave wid owns row-tile wid; 4 col tiles ----
    {
        short8 af = *(const short8*)(&Qb[(wid*16 + l15)*40 + quad*8]);
        #pragma unroll
        for (int j = 0; j < 4; j++) {
            short8 bfm = *(const short8*)(&Kb[(j*16 + l15)*40 + quad*8]);
            f32x4 acc = {0.f,0.f,0.f,0.f};
            acc = __builtin_amdgcn_mfma_f32_16x16x32_bf16(af, bfm, acc, 0, 0, 0);
            #pragma unroll
            for (int reg = 0; reg < 4; reg++)
                S[(wid*16 + quad*4 + reg)*57 + j*16 + l15] = acc[reg];
        }
    }
    __syncthreads();

    // ---- masked softmax over j<56, rows i<56 (one lane per row) ----
    if (tid < 56) {
        float mx = -1e30f;
        for (int j = 0; j < 56; j++) mx = fmaxf(mx, S[tid*57 + j]);
        float sum = 0.f;
        for (int j = 0; j < 56; j++) { float e = expf(S[tid*57+j] - mx); S[tid*57+j] = e; sum += e; }
        float inv = 1.0f / sum;
        for (int j = 0; j < 56; j++) S[tid*57+j] *= inv;
    }
    __syncthreads();

    // ---- P -> bf16 (A-operand layout source), zero the pads ----
    for (int t = tid; t < 64*64; t += 256) {
        int m = t >> 6, n = t & 63;
        float val = (m < 56 && n < 56) ? S[m*57 + n] : 0.f;
        Pb[m*72 + n] = f2bu(val);
    }
    __syncthreads();

    // ---- PV: O[m][d] = sum_j P[m][j] V[j][d]; 2 n-tiles, 2 k-chunks ----
    {
        f32x4 acc[2];
        acc[0] = (f32x4){0.f,0.f,0.f,0.f};
        acc[1] = (f32x4){0.f,0.f,0.f,0.f};
        #pragma unroll
        for (int k0 = 0; k0 < 64; k0 += 32) {
            short8 af = *(const short8*)(&Pb[(wid*16 + l15)*72 + k0 + quad*8]);
            #pragma unroll
            for (int nt = 0; nt < 2; nt++) {
                short8 bfm = *(const short8*)(&Vt[(nt*16 + l15)*80 + k0 + quad*8]);
                acc[nt] = __builtin_amdgcn_mfma_f32_16x16x32_bf16(af, bfm, acc[nt], 0, 0, 0);
            }
        }
        #pragma unroll
        for (int nt = 0; nt < 2; nt++) {
            #pragma unroll
            for (int reg = 0; reg < 4; reg++) {
                const int m = wid*16 + quad*4 + reg;
                const int d = nt*16 + l15;
                if (m < 56) {
                    float val = acc[nt][reg];
                    if (COLM) {
                        int hp = 7*nh + (m >> 3);
                        int wp = (m & 7)*7 + (line >> 3);
                        int cp = (line & 7)*32 + d;
                        size_t o = ((size_t)(b*HH + hp)*WWD + wp)*DD + cp;
                        outp[o] = __float2bfloat16(val + toF(lepe[o]));
                    } else {
                        outp[base + (size_t)m * rstr + d] = __float2bfloat16(val);
                    }
                }
            }
        }
    }
}

extern "C" void kernel_launch(void* const* d_in, const int* in_sizes, int n_in,
                              void* d_out, int out_size, void* d_ws, size_t ws_size,
                              hipStream_t stream)
{
    const float* x_in   = (const float*)d_in[0];
    const float* cpe_w  = (const float*)d_in[1];
    const float* cpe_b  = (const float*)d_in[2];
    const float* ln1_g  = (const float*)d_in[3];
    const float* ln1_b  = (const float*)d_in[4];
    const float* wq     = (const float*)d_in[5];
    const float* bq     = (const float*)d_in[6];
    const float* wk     = (const float*)d_in[7];
    const float* bk     = (const float*)d_in[8];
    const float* wv     = (const float*)d_in[9];
    const float* bv     = (const float*)d_in[10];
    const float* lepe_w = (const float*)d_in[11];
    const float* lepe_b = (const float*)d_in[12];
    const float* wo     = (const float*)d_in[13];
    const float* bo     = (const float*)d_in[14];
    const float* ln2_g  = (const float*)d_in[15];
    const float* ln2_b  = (const float*)d_in[16];
    const float* fc1_w  = (const float*)d_in[17];
    const float* fc1_b  = (const float*)d_in[18];
    const float* dw_w   = (const float*)d_in[19];
    const float* dw_b   = (const float*)d_in[20];
    const float* fc2_w  = (const float*)d_in[21];
    const float* fc2_b  = (const float*)d_in[22];
    float* out = (float*)d_out;                 // fp32 output (proven)

    const size_t ND = (size_t)NPIX * DD;
    float* X0  = (float*)d_ws;          // fp32 trunk residual 1
    float* ACC = X0 + ND;               // fp32 x1 / fc2 accumulator
    bf16*  B1  = (bf16*)(ACC + ND);     // xn1, then lepe
    bf16*  B2  = B1 + ND;               // q roped, then xn2
    bf16*  B3  = B2 + ND;               // k roped, then h1q
    bf16*  B4  = B3 + ND;               // v, then h2q
    bf16*  VWb   = (bf16*)d_out;        // d_out lo half: vw scratch
    bf16*  ATTNb = VWb + ND;            // d_out hi half: attn scrambled scratch

    dim3 b256(256);
    dim3 gridD(DD/64, NPIX/64);   // (4, 392)

    // 1. CPE: X0 = x + dwconv3x3(x)
    dwconv_kernel<3, float, float, true><<<NPIX, b256, 0, stream>>>(x_in, cpe_w, DD, cpe_b, X0, DD);
    // 2. LN1 -> B1
    ln_kernel<<<NPIX, b256, 0, stream>>>(X0, ln1_g, ln1_b, B1);
    // 3-5. Q,K,V projections (SCALE folded into K)
    mgemm_kernel<0><<<gridD, b256, 0, stream>>>(B1, wq, DD, bq, 1.0f, nullptr, nullptr, B2, nullptr, NPIX, DD, DD, 1.0f);
    mgemm_kernel<0><<<gridD, b256, 0, stream>>>(B1, wk, DD, bk, 1.0f, nullptr, nullptr, B3, nullptr, NPIX, DD, DD, SCALE_K);
    mgemm_kernel<0><<<gridD, b256, 0, stream>>>(B1, wv, DD, bv, 1.0f, nullptr, nullptr, B4, nullptr, NPIX, DD, DD, 1.0f);
    // 6. RoPE in place on q,k
    rope_kernel<<<(NPIX*128)/256, b256, 0, stream>>>(B2, B3);
    // 7. LEPE: B1 = dwconv5x5(v)
    dwconv_kernel<5, bf16, bf16, false><<<NPIX, b256, 0, stream>>>(B4, lepe_w, DD, lepe_b, B1, DD);
    // 8. Row attention (MFMA): (q,k,v) -> vw
    attn_mfma_kernel<false><<<HB*NHEAD*HH, b256, 0, stream>>>(B2, B3, B4, nullptr, VWb);
    // 9. Column attention (MFMA); scrambled write + lepe -> ATTNb
    attn_mfma_kernel<true><<<HB*NHEAD*WWD, b256, 0, stream>>>(B2, B3, VWb, B1, ATTNb);
    // 10. Output projection + residual: ACC = X0 + ATTNb*wo^T + bo
    mgemm_kernel<2><<<gridD, b256, 0, stream>>>(ATTNb, wo, DD, bo, 1.0f, X0, ACC, nullptr, nullptr, NPIX, DD, DD, 1.0f);
    // 11. LN2 -> B2
    ln_kernel<<<NPIX, b256, 0, stream>>>(ACC, ln2_g, ln2_b, B2);
    // 12-14 x4: FFN in four 256-channel quarters, fc2 accumulated into ACC
    for (int qtr = 0; qtr < 4; qtr++) {
        const int off = qtr * 256;
        mgemm_kernel<1><<<gridD, b256, 0, stream>>>(B2, fc1_w + (size_t)off*DD, DD, fc1_b + off, 1.0f,
                                                    nullptr, nullptr, B3, nullptr, NPIX, 256, DD, 1.0f);
        dwconv_kernel<3, bf16, bf16, true><<<NPIX, b256, 0, stream>>>(B3, dw_w + off, FFND, dw_b + off, B4, 256);
        if (qtr < 3)
            mgemm_kernel<4><<<gridD, b256, 0, stream>>>(B4, fc2_w + off, FFND, fc2_b, (qtr==0)?1.0f:0.0f,
                                                        nullptr, ACC, nullptr, nullptr, NPIX, DD, 256, 1.0f);
        else
            mgemm_kernel<5><<<gridD, b256, 0, stream>>>(B4, fc2_w + off, FFND, fc2_b, 0.0f,
                                                        nullptr, ACC, nullptr, out, NPIX, DD, 256, 1.0f);
    }
}